// Round 1
// baseline (436.205 us; speedup 1.0000x reference)
//
#include <hip/hip_runtime.h>
#include <hip/hip_bf16.h>

#define CHUNK 400
#define LWIN 50
#define JUMP 8
#define NCH 128
#define BCH 128
#define HCH 512
#define KDW 3
#define NBLK 14
#define BUF 516
#define EPSV 1e-8f

// ---------------- encoder: Conv1d(2->128, k=50, s=50) + ReLU ----------------
__global__ void k_encoder(const float* __restrict__ mix,
                          const float* __restrict__ Wenc,
                          float* __restrict__ enc) {
    int idx = blockIdx.x * 256 + threadIdx.x;   // 1024 = 128 ch * 8 frames
    if (idx >= NCH * JUMP) return;
    int n = idx >> 3, t = idx & 7;
    const float* w = Wenc + n * 100;            // [n][ic=2][50]
    const float* m = mix + t * LWIN;
    float s = 0.f;
    #pragma unroll 10
    for (int l = 0; l < LWIN; ++l) s += m[l] * w[l];          // ic = 0
    #pragma unroll 10
    for (int l = 0; l < LWIN; ++l) s += m[CHUNK + l] * w[LWIN + l]; // ic = 1
    enc[n * JUMP + t] = fmaxf(s, 0.f);
}

// ------------- ring-buffer shifts (both buffers) + xA staging ---------------
__global__ void k_bufcopy(const float* __restrict__ inEnc,
                          const float* __restrict__ inLn,
                          const float* __restrict__ enc,
                          float* __restrict__ outEnc,
                          float* __restrict__ outLn,
                          float* __restrict__ xA) {
    int t = blockIdx.x * 256 + threadIdx.x;
    int c = blockIdx.y;
    if (t >= BUF) return;
    int i = c * BUF + t;
    // encoder buffer: shift by JUMP, tail = fresh enc frames
    float ev = (t < BUF - JUMP) ? inEnc[i + JUMP] : enc[c * JUMP + (t - (BUF - JUMP))];
    outEnc[i] = ev;
    // layernorm buffer: shifted part only (tail written by k_front)
    if (t < BUF - JUMP) {
        float v = inLn[i + JUMP];
        outLn[i] = v;
        xA[t * BCH + c] = v;     // [T][C] layout for TCN
    }
}

// --------- front-end: cLN(enc) + bottleneck 1x1 (128x128), 8 frames --------
__global__ void k_front(const float* __restrict__ enc,
                        const float* __restrict__ g,
                        const float* __restrict__ b,
                        const float* __restrict__ Wbn,
                        float* __restrict__ outLn,
                        float* __restrict__ xA) {
    __shared__ float ns[NCH];
    __shared__ float wred[2][2];
    int t = blockIdx.x;       // 0..7
    int c = threadIdx.x;      // 0..127
    float e = enc[c * JUMP + t];
    float s = e, q = e * e;
    #pragma unroll
    for (int o = 32; o; o >>= 1) { s += __shfl_xor(s, o); q += __shfl_xor(q, o); }
    int lane = c & 63, w = c >> 6;
    if (lane == 0) { wred[w][0] = s; wred[w][1] = q; }
    __syncthreads();
    float S = wred[0][0] + wred[1][0], Q = wred[0][1] + wred[1][1];
    float mean = S * (1.f / NCH);
    float var = Q * (1.f / NCH) - mean * mean;
    float r = rsqrtf(var + EPSV);
    ns[c] = g[c] * (e - mean) * r + b[c];
    __syncthreads();
    float acc = 0.f;
    const float* wr = Wbn + c * NCH;
    #pragma unroll 8
    for (int j = 0; j < NCH; ++j) acc += wr[j] * ns[j];
    outLn[c * BUF + (BUF - JUMP) + t] = acc;
    xA[(BUF - JUMP + t) * BCH + c] = acc;
}

// ------- TCN stage 1: y1 = w1 @ x ; PReLU ; cLN  (8 frames per WG) ---------
__global__ __launch_bounds__(512) void k_stage1(
    const float* __restrict__ xIn, float* __restrict__ y1n,
    const float* __restrict__ w1, const float* __restrict__ p1v,
    const float* __restrict__ g1, const float* __restrict__ b1, int T) {
    __shared__ float xs[8 * BCH];
    __shared__ float red[8][8][2];   // [wave][frame][sum,sumsq]
    __shared__ float stats[8][2];    // [frame][mean,rstd]
    int t0 = blockIdx.x * 8;
    int nf = min(8, T - t0);
    for (int idx = threadIdx.x; idx < nf * BCH; idx += 512)
        xs[idx] = xIn[t0 * BCH + idx];
    __syncthreads();
    int h = threadIdx.x;
    float a = *p1v;
    float acc[8] = {0.f,0.f,0.f,0.f,0.f,0.f,0.f,0.f};
    const float* wr = w1 + h * BCH;
    for (int c = 0; c < BCH; ++c) {
        float wv = wr[c];
        #pragma unroll
        for (int f = 0; f < 8; ++f) acc[f] += wv * xs[f * BCH + c];
    }
    #pragma unroll
    for (int f = 0; f < 8; ++f) {
        float v = acc[f];
        acc[f] = (v >= 0.f) ? v : a * v;
    }
    int lane = h & 63, wid = h >> 6;
    for (int f = 0; f < nf; ++f) {
        float s = acc[f], q = acc[f] * acc[f];
        #pragma unroll
        for (int o = 32; o; o >>= 1) { s += __shfl_xor(s, o); q += __shfl_xor(q, o); }
        if (lane == 0) { red[wid][f][0] = s; red[wid][f][1] = q; }
    }
    __syncthreads();
    if (h < nf) {
        float s = 0.f, q = 0.f;
        #pragma unroll
        for (int w = 0; w < 8; ++w) { s += red[w][h][0]; q += red[w][h][1]; }
        float mean = s * (1.f / HCH);
        float var = q * (1.f / HCH) - mean * mean;
        stats[h][0] = mean;
        stats[h][1] = rsqrtf(var + EPSV);
    }
    __syncthreads();
    float gg = g1[h], bb = b1[h];
    for (int f = 0; f < nf; ++f)
        y1n[(t0 + f) * HCH + h] = gg * (acc[f] - stats[f][0]) * stats[f][1] + bb;
}

// -- TCN stage 2: dwconv(d) ; PReLU ; cLN ; y3 = w2 @ . ; residual (4 f/WG) --
__global__ __launch_bounds__(512) void k_stage2(
    const float* __restrict__ xIn, float* __restrict__ xOut,
    const float* __restrict__ y1n, const float* __restrict__ dw,
    const float* __restrict__ p2v, const float* __restrict__ g2,
    const float* __restrict__ b2, const float* __restrict__ w2,
    int Tout, int d) {
    __shared__ float ys[4 * 516];    // 512 per frame, +1 pad per 128 (stride 129)
    __shared__ float red[8][4][2];
    __shared__ float stats[4][2];
    int t0 = blockIdx.x * 4;
    int nf = min(4, Tout - t0);
    int h = threadIdx.x;
    float d0 = dw[h * 3 + 0], d1 = dw[h * 3 + 1], d2 = dw[h * 3 + 2];
    float a = *p2v;
    float y[4];
    for (int f = 0; f < nf; ++f) {
        int t = t0 + f;
        float v = d0 * y1n[t * HCH + h] + d1 * y1n[(t + d) * HCH + h]
                + d2 * y1n[(t + 2 * d) * HCH + h];
        y[f] = (v >= 0.f) ? v : a * v;
    }
    int lane = h & 63, wid = h >> 6;
    for (int f = 0; f < nf; ++f) {
        float s = y[f], q = y[f] * y[f];
        #pragma unroll
        for (int o = 32; o; o >>= 1) { s += __shfl_xor(s, o); q += __shfl_xor(q, o); }
        if (lane == 0) { red[wid][f][0] = s; red[wid][f][1] = q; }
    }
    __syncthreads();
    if (h < nf) {
        float s = 0.f, q = 0.f;
        #pragma unroll
        for (int w = 0; w < 8; ++w) { s += red[w][h][0]; q += red[w][h][1]; }
        float mean = s * (1.f / HCH);
        float var = q * (1.f / HCH) - mean * mean;
        stats[h][0] = mean;
        stats[h][1] = rsqrtf(var + EPSV);
    }
    __syncthreads();
    float gg = g2[h], bb = b2[h];
    int pad_idx = (h >> 7) * 129 + (h & 127);
    for (int f = 0; f < nf; ++f)
        ys[f * 516 + pad_idx] = gg * (y[f] - stats[f][0]) * stats[f][1] + bb;
    __syncthreads();
    int c = h >> 2, p = h & 3;
    float acc[4] = {0.f, 0.f, 0.f, 0.f};
    const float* wr = w2 + c * HCH + p * 128;
    const float* yb = ys + p * 129;
    for (int j = 0; j < 128; ++j) {
        float wv = wr[j];
        #pragma unroll
        for (int f = 0; f < 4; ++f) acc[f] += wv * yb[f * 516 + j];
    }
    for (int f = 0; f < nf; ++f) {
        acc[f] += __shfl_xor(acc[f], 1);
        acc[f] += __shfl_xor(acc[f], 2);
    }
    if (p == 0) {
        for (int f = 0; f < nf; ++f) {
            int t = t0 + f;
            xOut[t * BCH + c] = xIn[(t + 2 * d) * BCH + c] + acc[f];
        }
    }
}

// -------------- mask conv + ReLU ; mask encoder ; decoder basis -------------
__global__ void k_mask_dec(const float* __restrict__ xF,
                           const float* __restrict__ Wmask,
                           const float* __restrict__ Wdec,
                           const float* __restrict__ enc,
                           float* __restrict__ est) {
    __shared__ float xs[NCH];
    __shared__ float sw[NCH];
    int t = blockIdx.x;     // 0..7
    int c = threadIdx.x;    // 0..127
    xs[c] = xF[t * BCH + c];
    __syncthreads();
    float m = 0.f;
    const float* wr = Wmask + c * BCH;
    #pragma unroll 8
    for (int j = 0; j < BCH; ++j) m += wr[j] * xs[j];
    m = fmaxf(m, 0.f);
    sw[c] = m * enc[c * JUMP + t];
    __syncthreads();
    if (c < LWIN) {
        float e = 0.f;
        const float* wd = Wdec + c * NCH;
        #pragma unroll 8
        for (int n = 0; n < NCH; ++n) e += wd[n] * sw[n];
        est[t * LWIN + c] = e;
    }
}

extern "C" void kernel_launch(void* const* d_in, const int* in_sizes, int n_in,
                              void* d_out, int out_size, void* d_ws, size_t ws_size,
                              hipStream_t stream) {
    const float* mixture = (const float*)d_in[0];
    const float* inEnc   = (const float*)d_in[1];
    const float* inLn    = (const float*)d_in[2];
    const float* Wenc    = (const float*)d_in[3];
    const float* lng     = (const float*)d_in[4];
    const float* lnb     = (const float*)d_in[5];
    const float* Wbn     = (const float*)d_in[6];
    const float* w1      = (const float*)d_in[7];
    const float* p1      = (const float*)d_in[8];
    const float* g1      = (const float*)d_in[9];
    const float* b1      = (const float*)d_in[10];
    const float* dwc     = (const float*)d_in[11];
    const float* p2      = (const float*)d_in[12];
    const float* g2      = (const float*)d_in[13];
    const float* b2      = (const float*)d_in[14];
    const float* w2      = (const float*)d_in[15];
    const float* Wmask   = (const float*)d_in[16];
    const float* Wdec    = (const float*)d_in[17];

    float* est    = (float*)d_out;            // 400
    float* outEnc = est + CHUNK;              // 66048
    float* outLn  = outEnc + NCH * BUF;       // 66048

    float* ws   = (float*)d_ws;
    float* enc  = ws;                         // 1024
    float* xA   = enc + NCH * JUMP;           // 66048 ([T][C])
    float* xB   = xA + BCH * BUF;             // 66048
    float* y1n  = xB + BCH * BUF;             // 516*512

    k_encoder<<<4, 256, 0, stream>>>(mixture, Wenc, enc);
    k_bufcopy<<<dim3(3, 128), 256, 0, stream>>>(inEnc, inLn, enc, outEnc, outLn, xA);
    k_front<<<JUMP, NCH, 0, stream>>>(enc, lng, lnb, Wbn, outLn, xA);

    float* xin = xA;
    float* xout = xB;
    int T = BUF;
    for (int i = 0; i < NBLK; ++i) {
        int d = 1 << (i % 7);
        int Tout = T - 2 * d;
        k_stage1<<<(T + 7) / 8, 512, 0, stream>>>(
            xin, y1n, w1 + (size_t)i * HCH * BCH, p1 + i,
            g1 + i * HCH, b1 + i * HCH, T);
        k_stage2<<<(Tout + 3) / 4, 512, 0, stream>>>(
            xin, xout, y1n, dwc + i * HCH * KDW, p2 + i,
            g2 + i * HCH, b2 + i * HCH, w2 + (size_t)i * BCH * HCH,
            Tout, d);
        T = Tout;
        float* tmp = xin; xin = xout; xout = tmp;
    }

    k_mask_dec<<<JUMP, NCH, 0, stream>>>(xin, Wmask, Wdec, enc, est);
}